// Round 7
// baseline (244.449 us; speedup 1.0000x reference)
//
#include <hip/hip_runtime.h>
#include <hip/hip_fp16.h>

constexpr int N = 50000;        // nodes
constexpr int D = 64;           // feature dim
constexpr int E = 1600000;      // edges
constexpr int NBUCK = (N + 255) / 256;   // 196 buckets of 256 nodes (dst>>8)
constexpr int CPT = 8;                   // edges per thread in k_bucket
constexpr int BUCK_BLOCKS = (E + 256 * CPT - 1) / (256 * CPT);  // 782

// ---------------------------------------------------------------------------
// K1: per-bucket edge histogram (LDS-privatized)
__global__ void k_hist(const int* __restrict__ dst, int* __restrict__ ghist) {
    __shared__ int lh[NBUCK];
    int tid = threadIdx.x;
    for (int i = tid; i < NBUCK; i += 256) lh[i] = 0;
    __syncthreads();
    for (int e = blockIdx.x * 256 + tid; e < E; e += BUCK_BLOCKS * 256)
        atomicAdd(&lh[dst[e] >> 8], 1);
    __syncthreads();
    for (int i = tid; i < NBUCK; i += 256)
        if (lh[i]) atomicAdd(&ghist[i], lh[i]);
}

// K2: exclusive scan of bucket counts -> base[], cursor[]
__global__ void k_scan(const int* __restrict__ ghist, int* __restrict__ base,
                       int* __restrict__ cursor) {
    __shared__ int sm[256];
    int t = threadIdx.x;
    sm[t] = (t < NBUCK) ? ghist[t] : 0;
    __syncthreads();
    for (int off = 1; off < 256; off <<= 1) {
        int v = (t >= off) ? sm[t - off] : 0;
        __syncthreads();
        sm[t] += v;
        __syncthreads();
    }
    if (t < NBUCK) {
        int b = (t == 0) ? 0 : sm[t - 1];
        base[t] = b;
        cursor[t] = b;
    }
    if (t == 0) base[NBUCK] = E;
}

// K3: privatized counting-sort scatter -> bucket-grouped packed edges.
// packed = dst<<16 | src  (both < 65536).
__global__ void k_bucket(const int* __restrict__ src, const int* __restrict__ dst,
                         int* __restrict__ cursor, unsigned* __restrict__ packed) {
    __shared__ int lh[NBUCK];
    __shared__ int lb[NBUCK];
    int tid = threadIdx.x;
    for (int i = tid; i < NBUCK; i += 256) lh[i] = 0;
    __syncthreads();
    int base_e = blockIdx.x * (256 * CPT);
    unsigned pk[CPT];
    int bn[CPT], rk[CPT];
#pragma unroll
    for (int i = 0; i < CPT; ++i) {
        int e = base_e + i * 256 + tid;
        if (e < E) {
            int d = dst[e];
            int s = src[e];
            bn[i] = d >> 8;
            pk[i] = ((unsigned)d << 16) | (unsigned)s;
            rk[i] = atomicAdd(&lh[bn[i]], 1);
        } else bn[i] = -1;
    }
    __syncthreads();
    for (int i = tid; i < NBUCK; i += 256) {
        int c = lh[i];
        lb[i] = c ? atomicAdd(&cursor[i], c) : 0;
    }
    __syncthreads();
#pragma unroll
    for (int i = 0; i < CPT; ++i)
        if (bn[i] >= 0) packed[lb[bn[i]] + rk[i]] = pk[i];
}

// K4a: one block per bucket — local histogram + scan -> rowptr, cur, norm.
__global__ void k_csrhist(const int* __restrict__ base, const unsigned* __restrict__ packed,
                          int* __restrict__ rowptr, int* __restrict__ cur,
                          float* __restrict__ norm) {
    __shared__ int cnt[256];
    __shared__ int sm[256];
    int b = blockIdx.x, tid = threadIdx.x;
    if (tid < 256) cnt[tid] = 0;
    __syncthreads();
    int beg = base[b], end = base[b + 1];
    for (int j = beg + tid; j < end; j += 1024)
        atomicAdd(&cnt[(packed[j] >> 16) & 0xFF], 1);
    __syncthreads();
    if (tid < 256) sm[tid] = cnt[tid];
    __syncthreads();
    for (int off = 1; off < 256; off <<= 1) {
        int v = 0;
        if (tid < 256 && tid >= off) v = sm[tid - off];
        __syncthreads();
        if (tid < 256) sm[tid] += v;
        __syncthreads();
    }
    if (tid < 256) {
        int excl = (tid == 0) ? 0 : sm[tid - 1];
        int node = b * 256 + tid;
        if (node < N) {
            rowptr[node] = beg + excl;
            cur[node] = beg + excl;
            norm[node] = cnt[tid] ? rsqrtf((float)cnt[tid]) : 0.0f;
        }
        if (b == 0 && tid == 0) rowptr[N] = E;
    }
}

// K4b: flat fill — full-grid parallelism; u16 writes land inside each
// bucket's ~16 KB L2-resident window (packed is bucket-sorted), so no
// write amplification.
__global__ void k_csrfill(const unsigned* __restrict__ packed, int* __restrict__ cur,
                          unsigned short* __restrict__ csr) {
    int i = blockIdx.x * blockDim.x + threadIdx.x;   // uint4 index
    if (i >= E / 4) return;
    uint4 p4 = ((const uint4*)packed)[i];
#pragma unroll
    for (int k = 0; k < 4; ++k) {
        unsigned p = (k == 0) ? p4.x : (k == 1) ? p4.y : (k == 2) ? p4.z : p4.w;
        int node = p >> 16;
        int slot = atomicAdd(&cur[node], 1);
        csr[slot] = (unsigned short)(p & 0xFFFFu);
    }
}

// K5: h2[row][d] = (sum_k x[row][k] * W[k][d]) * norm[row], stored fp16
__global__ void k_gemm(const float* __restrict__ x, const float* __restrict__ W,
                       const float* __restrict__ norm, __half* __restrict__ h2) {
    __shared__ float Wl[64 * 64];
    __shared__ float xs[16][64];
    int tid = threadIdx.x;
    const float4* W4 = (const float4*)W;
    float4* Wl4 = (float4*)Wl;
    Wl4[tid] = W4[tid];
    int r = tid >> 6, d = tid & 63;
    int row = blockIdx.x * 16 + r;
    xs[r][d] = x[row * 64 + d];
    __syncthreads();
    float a = 0.0f;
#pragma unroll
    for (int k = 0; k < 64; ++k) a = fmaf(xs[r][k], Wl[k * 64 + d], a);
    h2[row * 64 + d] = __float2half(a * norm[row]);
}

// K6: fused aggregate + dst-norm + bias + softplus.
// One wave per node; lanes 0-31 take even edges, 32-63 odd edges; each lane
// loads a half2 (4B) so one wave op covers two full 128B rows. fp32 register
// accumulation, __shfl_xor(32) combine, float2 stores. No atomics.
__global__ void k_aggregate(const int* __restrict__ rowptr,
                            const unsigned short* __restrict__ csr,
                            const __half* __restrict__ h2, const float* __restrict__ norm,
                            const float* __restrict__ bias, float* __restrict__ out) {
    int node = blockIdx.x * 4 + (threadIdx.x >> 6);
    int lane = threadIdx.x & 63;
    int half = lane >> 5;          // which edge of the pair
    int fl = lane & 31;            // feature-pair index (features 2fl, 2fl+1)
    const __half2* h2v = (const __half2*)h2;   // row stride 32
    int beg = rowptr[node];
    int end = rowptr[node + 1];
    float ax = 0.0f, ay = 0.0f, bx = 0.0f, by = 0.0f;
    int j = beg;
    for (; j + 7 < end; j += 8) {            // 8 edges per wave iteration
        int s0 = csr[j + half];
        int s1 = csr[j + 2 + half];
        int s2 = csr[j + 4 + half];
        int s3 = csr[j + 6 + half];
        float2 v0 = __half22float2(h2v[s0 * 32 + fl]);
        float2 v1 = __half22float2(h2v[s1 * 32 + fl]);
        float2 v2 = __half22float2(h2v[s2 * 32 + fl]);
        float2 v3 = __half22float2(h2v[s3 * 32 + fl]);
        ax += v0.x + v2.x;  ay += v0.y + v2.y;
        bx += v1.x + v3.x;  by += v1.y + v3.y;
    }
    for (; j + 1 < end; j += 2) {            // pair tail
        int s = csr[j + half];
        float2 v = __half22float2(h2v[s * 32 + fl]);
        ax += v.x;  ay += v.y;
    }
    if (j < end && half == 0) {              // odd final edge
        int s = csr[j];
        float2 v = __half22float2(h2v[s * 32 + fl]);
        ax += v.x;  ay += v.y;
    }
    ax += bx;  ay += by;
    ax += __shfl_xor(ax, 32, 64);            // combine the two half-waves
    ay += __shfl_xor(ay, 32, 64);
    if (half == 0) {
        float nrm = norm[node];
        float2 bs = ((const float2*)bias)[fl];
        float vx = ax * nrm + bs.x;
        float vy = ay * nrm + bs.y;
        float2 o;
        o.x = fmaxf(vx, 0.0f) + log1pf(expf(-fabsf(vx)));
        o.y = fmaxf(vy, 0.0f) + log1pf(expf(-fabsf(vy)));
        ((float2*)out)[node * 32 + fl] = o;
    }
}

extern "C" void kernel_launch(void* const* d_in, const int* in_sizes, int n_in,
                              void* d_out, int out_size, void* d_ws, size_t ws_size,
                              hipStream_t stream) {
    // inputs: t(f32,1), x(f32,N*D), weight(f32,D*D), bias(f32,D), src(i32,E), dst(i32,E)
    const float* x    = (const float*)d_in[1];
    const float* W    = (const float*)d_in[2];
    const float* bias = (const float*)d_in[3];
    const int* src = (const int*)d_in[4];
    const int* dst = (const int*)d_in[5];
    float* out = (float*)d_out;

    // workspace layout (~16.8 MB; poisoned 0xAA every call — every buffer is
    // fully written before it is read)
    char* ws = (char*)d_ws;
    __half*         h2     = (__half*)(ws);                      // 6.4 MB
    unsigned*       packed = (unsigned*)(ws + 6400000);          // 6.4 MB
    unsigned short* csr    = (unsigned short*)(ws + 12800000);   // 3.2 MB
    int*            rowptr = (int*)(ws + 16000000);              // (N+1)*4
    int*            cur    = (int*)(ws + 16200008);              // N*4
    float*          norm   = (float*)(ws + 16400008);            // N*4
    int*            ghist  = (int*)(ws + 16600008);              // NBUCK
    int*            base   = (int*)(ws + 16600008 + 1024);       // NBUCK+1
    int*            cursor = (int*)(ws + 16600008 + 2048);       // NBUCK

    hipMemsetAsync(ghist, 0, NBUCK * sizeof(int), stream);

    k_hist     <<<BUCK_BLOCKS, 256, 0, stream>>>(dst, ghist);
    k_scan     <<<1, 256, 0, stream>>>(ghist, base, cursor);
    k_bucket   <<<BUCK_BLOCKS, 256, 0, stream>>>(src, dst, cursor, packed);
    k_csrhist  <<<NBUCK, 1024, 0, stream>>>(base, packed, rowptr, cur, norm);
    k_csrfill  <<<(E / 4 + 255) / 256, 256, 0, stream>>>(packed, cur, csr);
    k_gemm     <<<(N + 15) / 16, 1024, 0, stream>>>(x, W, norm, h2);
    k_aggregate<<<(N + 3) / 4, 256, 0, stream>>>(rowptr, csr, h2, norm, bias, out);
}

// Round 8
// 175.430 us; speedup vs baseline: 1.3934x; 1.3934x over previous
//
#include <hip/hip_runtime.h>
#include <hip/hip_fp16.h>

constexpr int N = 50000;        // nodes
constexpr int D = 64;           // feature dim
constexpr int E = 1600000;      // edges
constexpr int NBUCK = (N + 255) / 256;   // 196 buckets of 256 nodes (dst>>8)
constexpr int CAP = 10240;               // bucket window capacity (E/NBUCK=8163, sigma~90)
constexpr int CPT = 16;                  // edges per thread in k_bucket
constexpr int BUCK_BLOCKS = (E + 256 * CPT - 1) / (256 * CPT);  // 391

// ---------------------------------------------------------------------------
// K0: init per-bucket window cursors (cursor[b] = b*CAP)
__global__ void k_init(int* __restrict__ cursor) {
    int t = threadIdx.x;
    if (t < NBUCK) cursor[t] = t * CAP;
}

// K1: privatized counting-sort scatter -> fixed-capacity bucket windows.
// packed = dst<<16 | src (both < 65536). Per-(block,bucket) chunks contiguous.
__global__ void k_bucket(const int* __restrict__ src, const int* __restrict__ dst,
                         int* __restrict__ cursor, unsigned* __restrict__ packed) {
    __shared__ int lh[NBUCK];
    __shared__ int lb[NBUCK];
    int tid = threadIdx.x;
    for (int i = tid; i < NBUCK; i += 256) lh[i] = 0;
    __syncthreads();
    int base_e = blockIdx.x * (256 * CPT);
    unsigned pk[CPT];
    int bn[CPT], rk[CPT];
#pragma unroll
    for (int i = 0; i < CPT; ++i) {
        int e = base_e + i * 256 + tid;
        if (e < E) {
            int d = dst[e];
            int s = src[e];
            bn[i] = d >> 8;
            pk[i] = ((unsigned)d << 16) | (unsigned)s;
            rk[i] = atomicAdd(&lh[bn[i]], 1);
        } else bn[i] = -1;
    }
    __syncthreads();
    for (int i = tid; i < NBUCK; i += 256) {
        int c = lh[i];
        lb[i] = c ? atomicAdd(&cursor[i], c) : 0;   // one global atomic per bucket/block
    }
    __syncthreads();
#pragma unroll
    for (int i = 0; i < CPT; ++i)
        if (bn[i] >= 0) packed[lb[bn[i]] + rk[i]] = pk[i];
}

// K2: one block (1024 thr) per bucket — LDS histogram + scan -> rowptr/rowend/
// norm, then scatter src (u16) into the bucket's contiguous CSR window.
__global__ void k_csr(const int* __restrict__ cursor, const unsigned* __restrict__ packed,
                      unsigned short* __restrict__ csr, int* __restrict__ rowptr,
                      int* __restrict__ rowend, float* __restrict__ norm) {
    __shared__ int cnt[256];
    __shared__ int sm[256];
    __shared__ int cur[256];
    int b = blockIdx.x, tid = threadIdx.x;
    if (tid < 256) cnt[tid] = 0;
    __syncthreads();
    int beg = b * CAP;
    int end = cursor[b];                    // beg + count_b after k_bucket
    for (int j = beg + tid; j < end; j += 1024)
        atomicAdd(&cnt[(packed[j] >> 16) & 0xFF], 1);
    __syncthreads();
    if (tid < 256) sm[tid] = cnt[tid];
    __syncthreads();
    for (int off = 1; off < 256; off <<= 1) {
        int v = 0;
        if (tid < 256 && tid >= off) v = sm[tid - off];
        __syncthreads();
        if (tid < 256) sm[tid] += v;
        __syncthreads();
    }
    if (tid < 256) {
        int excl = (tid == 0) ? 0 : sm[tid - 1];
        int node = b * 256 + tid;
        if (node < N) {
            rowptr[node] = beg + excl;
            rowend[node] = beg + sm[tid];
            norm[node] = cnt[tid] ? rsqrtf((float)cnt[tid]) : 0.0f;
        }
        cur[tid] = beg + excl;
    }
    __syncthreads();
    for (int j = beg + tid; j < end; j += 1024) {
        unsigned p = packed[j];
        int slot = atomicAdd(&cur[(p >> 16) & 0xFF], 1);
        csr[slot] = (unsigned short)(p & 0xFFFFu);
    }
}

// K3: h2[row][d] = (sum_k x[row][k] * W[k][d]) * norm[row], stored fp16
__global__ void k_gemm(const float* __restrict__ x, const float* __restrict__ W,
                       const float* __restrict__ norm, __half* __restrict__ h2) {
    __shared__ float Wl[64 * 64];
    __shared__ float xs[16][64];
    int tid = threadIdx.x;
    const float4* W4 = (const float4*)W;
    float4* Wl4 = (float4*)Wl;
    Wl4[tid] = W4[tid];
    int r = tid >> 6, d = tid & 63;
    int row = blockIdx.x * 16 + r;
    xs[r][d] = x[row * 64 + d];
    __syncthreads();
    float a = 0.0f;
#pragma unroll
    for (int k = 0; k < 64; ++k) a = fmaf(xs[r][k], Wl[k * 64 + d], a);
    h2[row * 64 + d] = __float2half(a * norm[row]);
}

// K4: fused aggregate + dst-norm + bias + softplus.
// One wave per node; lanes 0-31 take even edges, 32-63 odd; each lane loads a
// half2 (4B) so one wave op covers two full 128B rows. fp32 register accum,
// __shfl_xor(32) combine, float2 stores. No atomics.
__global__ void k_aggregate(const int* __restrict__ rowptr, const int* __restrict__ rowend,
                            const unsigned short* __restrict__ csr,
                            const __half* __restrict__ h2, const float* __restrict__ norm,
                            const float* __restrict__ bias, float* __restrict__ out) {
    int node = blockIdx.x * 4 + (threadIdx.x >> 6);
    int lane = threadIdx.x & 63;
    int half = lane >> 5;          // which edge of the pair
    int fl = lane & 31;            // feature-pair index (features 2fl, 2fl+1)
    const __half2* h2v = (const __half2*)h2;   // row stride 32
    int beg = rowptr[node];
    int end = rowend[node];
    float ax = 0.0f, ay = 0.0f, bx = 0.0f, by = 0.0f;
    int j = beg;
    for (; j + 7 < end; j += 8) {            // 8 edges per wave iteration
        int s0 = csr[j + half];
        int s1 = csr[j + 2 + half];
        int s2 = csr[j + 4 + half];
        int s3 = csr[j + 6 + half];
        float2 v0 = __half22float2(h2v[s0 * 32 + fl]);
        float2 v1 = __half22float2(h2v[s1 * 32 + fl]);
        float2 v2 = __half22float2(h2v[s2 * 32 + fl]);
        float2 v3 = __half22float2(h2v[s3 * 32 + fl]);
        ax += v0.x + v2.x;  ay += v0.y + v2.y;
        bx += v1.x + v3.x;  by += v1.y + v3.y;
    }
    for (; j + 1 < end; j += 2) {            // pair tail
        int s = csr[j + half];
        float2 v = __half22float2(h2v[s * 32 + fl]);
        ax += v.x;  ay += v.y;
    }
    if (j < end && half == 0) {              // odd final edge
        int s = csr[j];
        float2 v = __half22float2(h2v[s * 32 + fl]);
        ax += v.x;  ay += v.y;
    }
    ax += bx;  ay += by;
    ax += __shfl_xor(ax, 32, 64);            // combine the two half-waves
    ay += __shfl_xor(ay, 32, 64);
    if (half == 0) {
        float nrm = norm[node];
        float2 bs = ((const float2*)bias)[fl];
        float vx = ax * nrm + bs.x;
        float vy = ay * nrm + bs.y;
        float2 o;
        o.x = fmaxf(vx, 0.0f) + log1pf(expf(-fabsf(vx)));
        o.y = fmaxf(vy, 0.0f) + log1pf(expf(-fabsf(vy)));
        ((float2*)out)[node * 32 + fl] = o;
    }
}

extern "C" void kernel_launch(void* const* d_in, const int* in_sizes, int n_in,
                              void* d_out, int out_size, void* d_ws, size_t ws_size,
                              hipStream_t stream) {
    // inputs: t(f32,1), x(f32,N*D), weight(f32,D*D), bias(f32,D), src(i32,E), dst(i32,E)
    const float* x    = (const float*)d_in[1];
    const float* W    = (const float*)d_in[2];
    const float* bias = (const float*)d_in[3];
    const int* src = (const int*)d_in[4];
    const int* dst = (const int*)d_in[5];
    float* out = (float*)d_out;

    // workspace layout (~19.3 MB; poisoned 0xAA every call — every buffer is
    // fully written before it is read)
    char* ws = (char*)d_ws;
    __half*         h2     = (__half*)(ws);                        // 6.4 MB
    unsigned*       packed = (unsigned*)(ws + 6400000);            // NBUCK*CAP*4 = 8.03 MB
    unsigned short* csr    = (unsigned short*)(ws + 14427136);     // NBUCK*CAP*2 = 4.01 MB
    int*            rowptr = (int*)(ws + 18440704);                // N*4
    int*            rowend = (int*)(ws + 18640704);                // N*4
    float*          norm   = (float*)(ws + 18840704);              // N*4
    int*            cursor = (int*)(ws + 19040704);                // NBUCK

    k_init     <<<1, 256, 0, stream>>>(cursor);
    k_bucket   <<<BUCK_BLOCKS, 256, 0, stream>>>(src, dst, cursor, packed);
    k_csr      <<<NBUCK, 1024, 0, stream>>>(cursor, packed, csr, rowptr, rowend, norm);
    k_gemm     <<<(N + 15) / 16, 1024, 0, stream>>>(x, W, norm, h2);
    k_aggregate<<<(N + 3) / 4, 256, 0, stream>>>(rowptr, rowend, csr, h2, norm, bias, out);
}